// Round 5
// baseline (849.994 us; speedup 1.0000x reference)
//
#include <hip/hip_runtime.h>

typedef unsigned short u16;
typedef unsigned int u32;

typedef __attribute__((ext_vector_type(8))) short short8;
typedef __attribute__((ext_vector_type(4))) float floatx4;

// ---------- bf16 helpers ----------
static __device__ __forceinline__ u16 f2b(float f) {
    union { float f; u32 i; } v; v.f = f;
    u32 r = v.i + 0x7fffu + ((v.i >> 16) & 1u);
    return (u16)(r >> 16);
}
// pack two floats to bf16x2 dword (round-half-up)
static __device__ __forceinline__ u32 pkbf(float a, float b) {
    u32 ia = __float_as_uint(a) + 0x8000u;
    u32 ib = __float_as_uint(b) + 0x8000u;
    return (ia >> 16) | (ib & 0xffff0000u);
}
// 2^x via v_exp_f32
static __device__ __forceinline__ float exp2f_hw(float x) {
    return __builtin_amdgcn_exp2f(x);
}

static __device__ __forceinline__ floatx4 mfma16(short8 a, short8 b, floatx4 c) {
    return __builtin_amdgcn_mfma_f32_16x16x32_bf16(a, b, c, 0, 0, 0);
}

// async global->LDS, 16B per lane; LDS dest must be wave-uniform base (HW adds lane*16)
typedef __attribute__((address_space(1))) const void gas_void;
typedef __attribute__((address_space(3))) void las_void;
static __device__ __forceinline__ void gl_lds16(const void* g, void* l) {
    __builtin_amdgcn_global_load_lds((gas_void*)g, (las_void*)l, 16, 0, 0);
}

#define B_ 4
#define S_ 2048
#define D_ 1024
#define H_ 16
#define DH_ 64
#define F_ 4096

// (1/8) * log2(e), folded into wq/bq so logits come out in exp2 domain
#define QSCALE 0.18033688011112042f

// ---------- cast fp32 -> bf16, 4 elems/thread ----------
__global__ __launch_bounds__(256) void cast_b(const float* __restrict__ in,
                                              u16* __restrict__ out, int n4) {
    int id = blockIdx.x * 256 + threadIdx.x;
    if (id < n4) {
        float4 v = ((const float4*)in)[id];
        ushort4 u;
        u.x = f2b(v.x); u.y = f2b(v.y); u.z = f2b(v.z); u.w = f2b(v.w);
        ((ushort4*)out)[id] = u;
    }
}

// ---------- transpose + cast + scale: in [R x C] fp32 -> out [C x R] bf16 ----------
__global__ void transpose_cast(const float* __restrict__ in, u16* __restrict__ out,
                               int R, int C, float scale) {
    __shared__ float t[32][33];
    int bx = blockIdx.x;  // over C
    int by = blockIdx.y;  // over R
    int x = threadIdx.x, y = threadIdx.y;  // 32x8
#pragma unroll
    for (int i = 0; i < 4; ++i) {
        int r = by * 32 + y + i * 8;
        t[y + i * 8][x] = in[(size_t)r * C + bx * 32 + x];
    }
    __syncthreads();
#pragma unroll
    for (int i = 0; i < 4; ++i) {
        int c = bx * 32 + y + i * 8;
        out[(size_t)c * R + by * 32 + x] = f2b(t[x][y + i * 8] * scale);
    }
}

// ---------- transpose V: [B,S,H,DH] bf16 -> [B,H,DH,S] bf16 ----------
__global__ void transpose_v(const u16* __restrict__ v, u16* __restrict__ vt) {
    __shared__ u16 t[32][33];
    int bh = blockIdx.z; int b = bh >> 4, h = bh & 15;
    int s0 = blockIdx.x * 32, d0 = blockIdx.y * 32;
    int x = threadIdx.x, y = threadIdx.y;  // 32x8
#pragma unroll
    for (int i = 0; i < 4; ++i)
        t[y + i * 8][x] = v[((size_t)(b * S_ + s0 + y + i * 8)) * D_ + h * DH_ + d0 + x];
    __syncthreads();
#pragma unroll
    for (int i = 0; i < 4; ++i)
        vt[((size_t)bh * DH_ + d0 + y + i * 8) * S_ + s0 + x] = t[x][y + i * 8];
}

// ---------- generic bf16 GEMM: C[M,N] = A[M,K] @ Bt[N,K]^T (+bias*bscale)(+relu) ----------
// 128x128 tile, 256 threads (4 waves in 2x2 of 64x64), BK=32, mfma 16x16x32.
// Staging via global_load_lds width=16 (m97 structure).
__global__ __launch_bounds__(256) void gemm_bt(const u16* __restrict__ A,
                                               const u16* __restrict__ Bt,
                                               const float* __restrict__ bias,
                                               float* __restrict__ outF,
                                               u16* __restrict__ outB,
                                               int M, int N, int K, int relu,
                                               float bscale) {
    __shared__ __align__(16) u16 sA[128 * 32];
    __shared__ __align__(16) u16 sB[128 * 32];

    int tid = threadIdx.x;
    int w = tid >> 6, lane = tid & 63, quad = lane >> 4, l = lane & 15;
    int wr = w >> 1, wc = w & 1;
    int bM = blockIdx.y, bN = blockIdx.x;

    floatx4 acc[4][4];
#pragma unroll
    for (int i = 0; i < 4; ++i)
#pragma unroll
        for (int j = 0; j < 4; ++j) acc[i][j] = (floatx4){0.f, 0.f, 0.f, 0.f};

    int r0 = lane >> 2;            // 0..15 row within wave's 16-row slab
    int c0 = (lane & 3) * 8;       // k-chunk (u16)

    for (int kk = 0; kk < K; kk += 32) {
#pragma unroll
        for (int hh = 0; hh < 2; ++hh) {
            int row = hh * 64 + w * 16 + r0;
            u16* lbase_a = &sA[(hh * 64 + w * 16) * 32];  // wave-uniform
            u16* lbase_b = &sB[(hh * 64 + w * 16) * 32];
            gl_lds16(&A[(size_t)(bM * 128 + row) * K + kk + c0], lbase_a);
            gl_lds16(&Bt[(size_t)(bN * 128 + row) * K + kk + c0], lbase_b);
        }
        __syncthreads();

        short8 af[4], bfr[4];
#pragma unroll
        for (int mt = 0; mt < 4; ++mt) {
            int m = wr * 64 + mt * 16 + l;
            af[mt] = *(const short8*)&sA[m * 32 + quad * 8];
        }
#pragma unroll
        for (int nt = 0; nt < 4; ++nt) {
            int n = wc * 64 + nt * 16 + l;
            bfr[nt] = *(const short8*)&sB[n * 32 + quad * 8];
        }
#pragma unroll
        for (int mt = 0; mt < 4; ++mt)
#pragma unroll
            for (int nt = 0; nt < 4; ++nt)
                acc[mt][nt] = mfma16(af[mt], bfr[nt], acc[mt][nt]);
        __syncthreads();
    }

    // epilogue
#pragma unroll
    for (int nt = 0; nt < 4; ++nt) {
        int colg = bN * 128 + wc * 64 + nt * 16 + l;
        float bv = bias ? bias[colg] * bscale : 0.f;
#pragma unroll
        for (int mt = 0; mt < 4; ++mt) {
#pragma unroll
            for (int r = 0; r < 4; ++r) {
                int rowg = bM * 128 + wr * 64 + mt * 16 + quad * 4 + r;
                float v = acc[mt][nt][r] + bv;
                if (relu) v = fmaxf(v, 0.f);
                size_t idx = (size_t)rowg * N + colg;
                if (outF) outF[idx] = v;
                if (outB) outB[idx] = f2b(v);
            }
        }
    }
}

// ---------- flash attention v3: no-max softmax, double-buffered P (PV reads the
// PREVIOUS iteration's P -> LDS latency spans a whole iteration), merged
// S-MFMA/exp2/pack per key-16-slice, manual pointer strength reduction.
// One block = (b,h) x 128 q-rows, 4 waves x 32 q-rows. grid: (S/128, B*H).
// Q pre-scaled by QSCALE, so P = 2^s directly.
#define PSTR 72              // P row stride in bf16 (64 keys + 8 pad)
#define PBUF (32 * PSTR)     // one wave's P tile
__global__ __launch_bounds__(256, 3) void attn_kernel(const u16* __restrict__ qb,
                                                      const u16* __restrict__ kb,
                                                      const u16* __restrict__ vt,
                                                      u16* __restrict__ ctx) {
    __shared__ __align__(16) u16 Ps[8 * PBUF];  // 36.9 KB: [buf][wave][32][PSTR]

    int bh = blockIdx.y; int b = bh >> 4, h = bh & 15;
    int tid = threadIdx.x;
    int w = tid >> 6, lane = tid & 63, quad = lane >> 4, l = lane & 15;
    int qw = blockIdx.x * 128 + w * 32;  // this wave's first q-row
    u16* Pbase = &Ps[w * PBUF];

    // Q fragments, B-operand: B[n = l][k = quad*8+j], kept in registers
    short8 qf[2][2];
#pragma unroll
    for (int nt = 0; nt < 2; ++nt)
#pragma unroll
        for (int kf = 0; kf < 2; ++kf)
            qf[nt][kf] = *(const short8*)(qb +
                ((size_t)(b * S_ + qw + nt * 16 + l)) * D_ + h * DH_ + kf * 32 + quad * 8);

    float lrp0 = 0.f, lrp1 = 0.f;  // per-lane partial denominators
    floatx4 O[2][4];
#pragma unroll
    for (int i = 0; i < 2; ++i)
#pragma unroll
        for (int j = 0; j < 4; ++j) O[i][j] = (floatx4){0.f, 0.f, 0.f, 0.f};

    // persistent row pointers (strength-reduced addressing)
    const u16* kp[4];  // K rows mt*16+l, advanced by 64*D_ per tile
    const u16* vp[4];  // V^T rows nd*16+l, advanced by 64 per tile
#pragma unroll
    for (int mt = 0; mt < 4; ++mt)
        kp[mt] = kb + ((size_t)(b * S_ + mt * 16 + l)) * D_ + h * DH_ + quad * 8;
#pragma unroll
    for (int nd = 0; nd < 4; ++nd)
        vp[nd] = vt + ((size_t)bh * DH_ + nd * 16 + l) * S_ + quad * 8;

    short8 kc[4][2];
    // load K(0)
#pragma unroll
    for (int mt = 0; mt < 4; ++mt) {
        kc[mt][0] = *(const short8*)kp[mt];
        kc[mt][1] = *(const short8*)(kp[mt] + 32);
        kp[mt] += 64 * D_;
    }

    // merged: S^T MFMA from kc, reload kc <- *kp (next tile), exp2 + pack -> Pw
    auto sstep = [&](u16* Pw) {
#pragma unroll
        for (int mt = 0; mt < 4; ++mt) {
            floatx4 s0 = (floatx4){0.f, 0.f, 0.f, 0.f};
            floatx4 s1 = (floatx4){0.f, 0.f, 0.f, 0.f};
            s0 = mfma16(kc[mt][0], qf[0][0], s0);
            s0 = mfma16(kc[mt][1], qf[0][1], s0);
            s1 = mfma16(kc[mt][0], qf[1][0], s1);
            s1 = mfma16(kc[mt][1], qf[1][1], s1);
            kc[mt][0] = *(const short8*)kp[mt];
            kc[mt][1] = *(const short8*)(kp[mt] + 32);
            kp[mt] += 64 * D_;
            float e0 = exp2f_hw(s0[0]), e1 = exp2f_hw(s0[1]);
            float e2 = exp2f_hw(s0[2]), e3 = exp2f_hw(s0[3]);
            lrp0 += (e0 + e1) + (e2 + e3);
            uint2 pk0; pk0.x = pkbf(e0, e1); pk0.y = pkbf(e2, e3);
            *(uint2*)&Pw[l * PSTR + mt * 16 + quad * 4] = pk0;
            e0 = exp2f_hw(s1[0]); e1 = exp2f_hw(s1[1]);
            e2 = exp2f_hw(s1[2]); e3 = exp2f_hw(s1[3]);
            lrp1 += (e0 + e1) + (e2 + e3);
            uint2 pk1; pk1.x = pkbf(e0, e1); pk1.y = pkbf(e2, e3);
            *(uint2*)&Pw[(16 + l) * PSTR + mt * 16 + quad * 4] = pk1;
        }
    };

    sstep(Pbase);  // P(0) -> buf0; kc now holds K(1)

    for (int kt = 0; kt < S_ / 64; ++kt) {
        u16* Pr = Pbase + (kt & 1) * (4 * PBUF);
        u16* Pw = Pbase + ((kt + 1) & 1) * (4 * PBUF);

        // V(kt) fragments — issue early
        short8 vf[4][2];
#pragma unroll
        for (int nd = 0; nd < 4; ++nd) {
            vf[nd][0] = *(const short8*)vp[nd];
            vf[nd][1] = *(const short8*)(vp[nd] + 32);
            vp[nd] += 64;
        }
        // P(kt) fragments from last iteration's buffer
        short8 pa[2][2];
#pragma unroll
        for (int mo = 0; mo < 2; ++mo)
#pragma unroll
            for (int kf = 0; kf < 2; ++kf)
                pa[mo][kf] = *(const short8*)&Pr[(mo * 16 + l) * PSTR + kf * 32 + quad * 8];

        if (kt < S_ / 64 - 1) sstep(Pw);  // S(kt+1) -> other buffer

        // O += P(kt) @ V(kt)
#pragma unroll
        for (int kf = 0; kf < 2; ++kf)
#pragma unroll
            for (int nd = 0; nd < 4; ++nd)
#pragma unroll
                for (int mo = 0; mo < 2; ++mo)
                    O[mo][nd] = mfma16(pa[mo][kf], vf[nd][kf], O[mo][nd]);
    }

    // ---- epilogue: reduce lr across quads, O /= lsum, store bf16 ----
    lrp0 += __shfl_xor(lrp0, 16); lrp0 += __shfl_xor(lrp0, 32);
    lrp1 += __shfl_xor(lrp1, 16); lrp1 += __shfl_xor(lrp1, 32);
    float lrv[2] = {lrp0, lrp1};
#pragma unroll
    for (int mo = 0; mo < 2; ++mo) {
        float invl = 1.0f / lrv[mo];
        float i0 = __shfl(invl, quad * 4 + 0);
        float i1 = __shfl(invl, quad * 4 + 1);
        float i2 = __shfl(invl, quad * 4 + 2);
        float i3 = __shfl(invl, quad * 4 + 3);
#pragma unroll
        for (int nd = 0; nd < 4; ++nd) {
            size_t base = ((size_t)(b * S_ + qw + mo * 16 + quad * 4)) * D_ + h * DH_ + nd * 16 + l;
            ctx[base]          = f2b(O[mo][nd][0] * i0);
            ctx[base + D_]     = f2b(O[mo][nd][1] * i1);
            ctx[base + 2 * D_] = f2b(O[mo][nd][2] * i2);
            ctx[base + 3 * D_] = f2b(O[mo][nd][3] * i3);
        }
    }
}

// ---------- fused add + layernorm (one row of 1024 per block) ----------
__global__ __launch_bounds__(256) void add_ln(const float* __restrict__ a,
                                              const float* __restrict__ b,
                                              const float* __restrict__ g,
                                              const float* __restrict__ be,
                                              float* __restrict__ outF,
                                              u16* __restrict__ outB) {
    int row = blockIdx.x, tid = threadIdx.x;
    size_t base = (size_t)row * D_;
    float4 va = ((const float4*)(a + base))[tid];
    float4 vb = ((const float4*)(b + base))[tid];
    float x0 = va.x + vb.x, x1 = va.y + vb.y, x2 = va.z + vb.z, x3 = va.w + vb.w;
    float s1 = x0 + x1 + x2 + x3;
    float s2 = x0 * x0 + x1 * x1 + x2 * x2 + x3 * x3;
#pragma unroll
    for (int off = 32; off; off >>= 1) {
        s1 += __shfl_xor(s1, off);
        s2 += __shfl_xor(s2, off);
    }
    __shared__ float r1[4], r2[4];
    int w = tid >> 6, lane = tid & 63;
    if (lane == 0) { r1[w] = s1; r2[w] = s2; }
    __syncthreads();
    s1 = r1[0] + r1[1] + r1[2] + r1[3];
    s2 = r2[0] + r2[1] + r2[2] + r2[3];
    float mean = s1 * (1.0f / D_);
    float var = s2 * (1.0f / D_) - mean * mean;
    float inv = rsqrtf(var + 1e-6f);
    float4 vg = ((const float4*)g)[tid];
    float4 vbe = ((const float4*)be)[tid];
    float o0 = (x0 - mean) * inv * vg.x + vbe.x;
    float o1 = (x1 - mean) * inv * vg.y + vbe.y;
    float o2 = (x2 - mean) * inv * vg.z + vbe.z;
    float o3 = (x3 - mean) * inv * vg.w + vbe.w;
    float4 o; o.x = o0; o.y = o1; o.z = o2; o.w = o3;
    ((float4*)(outF + base))[tid] = o;
    if (outB) {
        ushort4 u;
        u.x = f2b(o0); u.y = f2b(o1); u.z = f2b(o2); u.w = f2b(o3);
        ((ushort4*)(outB + base))[tid] = u;
    }
}

extern "C" void kernel_launch(void* const* d_in, const int* in_sizes, int n_in,
                              void* d_out, int out_size, void* d_ws, size_t ws_size,
                              hipStream_t stream) {
    const float* x   = (const float*)d_in[0];
    const float* wq  = (const float*)d_in[1];
    const float* bq  = (const float*)d_in[2];
    const float* wk  = (const float*)d_in[3];
    const float* bk  = (const float*)d_in[4];
    const float* wv  = (const float*)d_in[5];
    const float* bv  = (const float*)d_in[6];
    const float* wo  = (const float*)d_in[7];
    const float* bo  = (const float*)d_in[8];
    const float* w1  = (const float*)d_in[9];
    const float* b1  = (const float*)d_in[10];
    const float* w2  = (const float*)d_in[11];
    const float* b2  = (const float*)d_in[12];
    const float* g1  = (const float*)d_in[13];
    const float* be1 = (const float*)d_in[14];
    const float* g2  = (const float*)d_in[15];
    const float* be2 = (const float*)d_in[16];
    float* out = (float*)d_out;
    char* ws = (char*)d_ws;
    const size_t MB = 1u << 20;

    u16* xb    = (u16*)(ws + 0);        // 16 MB
    u16* wqT   = (u16*)(ws + 16 * MB);  // 2 MB
    u16* wkT   = (u16*)(ws + 18 * MB);
    u16* wvT   = (u16*)(ws + 20 * MB);
    u16* woT   = (u16*)(ws + 22 * MB);
    u16* w1T   = (u16*)(ws + 24 * MB);  // 8 MB
    u16* w2T   = (u16*)(ws + 32 * MB);  // 8 MB
    u16* qb    = (u16*)(ws + 40 * MB);  // 16 MB
    u16* kb    = (u16*)(ws + 56 * MB);  // 16 MB
    u16* vb    = (u16*)(ws + 72 * MB);  // 16 MB
    u16* vtb   = (u16*)(ws + 88 * MB);  // 16 MB
    u16* ctxb  = (u16*)(ws + 104 * MB); // 16 MB
    float* attn_out = (float*)(ws + 120 * MB); // 32 MB
    float* out1     = (float*)(ws + 152 * MB); // 32 MB
    u16* out1b      = (u16*)(ws + 184 * MB);   // 16 MB -> total 200 MB
    u16* hidden     = (u16*)(ws + 40 * MB);    // aliases q/k/v/vT (dead by then)
    float* ffn2out  = (float*)(ws + 120 * MB); // aliases attn_out (dead by then)

    dim3 tb(32, 8);

    // prep: casts + weight transposes (wq/bq pre-scaled by QSCALE = log2(e)/8)
    cast_b<<<8192, 256, 0, stream>>>(x, xb, (B_ * S_ * D_) / 4);
    transpose_cast<<<dim3(32, 32), tb, 0, stream>>>(wq, wqT, D_, D_, QSCALE);
    transpose_cast<<<dim3(32, 32), tb, 0, stream>>>(wk, wkT, D_, D_, 1.0f);
    transpose_cast<<<dim3(32, 32), tb, 0, stream>>>(wv, wvT, D_, D_, 1.0f);
    transpose_cast<<<dim3(32, 32), tb, 0, stream>>>(wo, woT, D_, D_, 1.0f);
    transpose_cast<<<dim3(128, 32), tb, 0, stream>>>(w1, w1T, D_, F_, 1.0f);
    transpose_cast<<<dim3(32, 128), tb, 0, stream>>>(w2, w2T, F_, D_, 1.0f);

    // QKV projections
    gemm_bt<<<dim3(8, 64), 256, 0, stream>>>(xb, wqT, bq, nullptr, qb, B_ * S_, D_, D_, 0, QSCALE);
    gemm_bt<<<dim3(8, 64), 256, 0, stream>>>(xb, wkT, bk, nullptr, kb, B_ * S_, D_, D_, 0, 1.0f);
    gemm_bt<<<dim3(8, 64), 256, 0, stream>>>(xb, wvT, bv, nullptr, vb, B_ * S_, D_, D_, 0, 1.0f);
    transpose_v<<<dim3(S_ / 32, DH_ / 32, B_ * H_), tb, 0, stream>>>(vb, vtb);

    // attention (flash-style, double-buffered P pipeline)
    attn_kernel<<<dim3(S_ / 128, B_ * H_), 256, 0, stream>>>(qb, kb, vtb, ctxb);

    // output projection (fp32 out, residual+LN done separately)
    gemm_bt<<<dim3(8, 64), 256, 0, stream>>>(ctxb, woT, bo, attn_out, nullptr, B_ * S_, D_, D_, 0, 1.0f);
    add_ln<<<B_ * S_, 256, 0, stream>>>(x, attn_out, g1, be1, out1, out1b);

    // FFN
    gemm_bt<<<dim3(32, 64), 256, 0, stream>>>(out1b, w1T, b1, nullptr, hidden, B_ * S_, F_, D_, 1, 1.0f);
    gemm_bt<<<dim3(8, 64), 256, 0, stream>>>(hidden, w2T, b2, ffn2out, nullptr, B_ * S_, D_, F_, 0, 1.0f);
    add_ln<<<B_ * S_, 256, 0, stream>>>(out1, ffn2out, g2, be2, out, nullptr);
}

// Round 6
// 776.816 us; speedup vs baseline: 1.0942x; 1.0942x over previous
//
#include <hip/hip_runtime.h>

typedef unsigned short u16;
typedef unsigned int u32;

typedef __attribute__((ext_vector_type(8))) short short8;
typedef __attribute__((ext_vector_type(4))) float floatx4;

// ---------- bf16 helpers ----------
static __device__ __forceinline__ u16 f2b(float f) {
    union { float f; u32 i; } v; v.f = f;
    u32 r = v.i + 0x7fffu + ((v.i >> 16) & 1u);
    return (u16)(r >> 16);
}
// pack two floats to bf16x2 dword (round-half-up)
static __device__ __forceinline__ u32 pkbf(float a, float b) {
    u32 ia = __float_as_uint(a) + 0x8000u;
    u32 ib = __float_as_uint(b) + 0x8000u;
    return (ia >> 16) | (ib & 0xffff0000u);
}
// 2^x via v_exp_f32
static __device__ __forceinline__ float exp2f_hw(float x) {
    return __builtin_amdgcn_exp2f(x);
}

static __device__ __forceinline__ floatx4 mfma16(short8 a, short8 b, floatx4 c) {
    return __builtin_amdgcn_mfma_f32_16x16x32_bf16(a, b, c, 0, 0, 0);
}

// async global->LDS, 16B per lane; LDS dest must be wave-uniform base (HW adds lane*16)
typedef __attribute__((address_space(1))) const void gas_void;
typedef __attribute__((address_space(3))) void las_void;
static __device__ __forceinline__ void gl_lds16(const void* g, void* l) {
    __builtin_amdgcn_global_load_lds((gas_void*)g, (las_void*)l, 16, 0, 0);
}

#define B_ 4
#define S_ 2048
#define D_ 1024
#define H_ 16
#define DH_ 64
#define F_ 4096
#define QKVS 3072   // row stride of fused qkv output

// (1/8) * log2(e), folded into wq/bq so logits come out in exp2 domain
#define QSCALE 0.18033688011112042f

// ---------- cast fp32 -> bf16, 4 elems/thread ----------
__global__ __launch_bounds__(256) void cast_b(const float* __restrict__ in,
                                              u16* __restrict__ out, int n4) {
    int id = blockIdx.x * 256 + threadIdx.x;
    if (id < n4) {
        float4 v = ((const float4*)in)[id];
        ushort4 u;
        u.x = f2b(v.x); u.y = f2b(v.y); u.z = f2b(v.z); u.w = f2b(v.w);
        ((ushort4*)out)[id] = u;
    }
}

// ---------- concat + scale bias: [bq*QSCALE | bk | bv] -> 3072 floats ----------
__global__ __launch_bounds__(256) void concat_bias(const float* __restrict__ bq,
                                                   const float* __restrict__ bk,
                                                   const float* __restrict__ bv,
                                                   float* __restrict__ o) {
    int i = blockIdx.x * 256 + threadIdx.x;
    float v;
    if (i < 1024) v = bq[i] * QSCALE;
    else if (i < 2048) v = bk[i - 1024];
    else v = bv[i - 2048];
    o[i] = v;
}

// ---------- transpose + cast + scale: in [R x C] fp32 -> out [C x R] bf16 ----------
__global__ void transpose_cast(const float* __restrict__ in, u16* __restrict__ out,
                               int R, int C, float scale) {
    __shared__ float t[32][33];
    int bx = blockIdx.x;  // over C
    int by = blockIdx.y;  // over R
    int x = threadIdx.x, y = threadIdx.y;  // 32x8
#pragma unroll
    for (int i = 0; i < 4; ++i) {
        int r = by * 32 + y + i * 8;
        t[y + i * 8][x] = in[(size_t)r * C + bx * 32 + x];
    }
    __syncthreads();
#pragma unroll
    for (int i = 0; i < 4; ++i) {
        int c = bx * 32 + y + i * 8;
        out[(size_t)c * R + by * 32 + x] = f2b(t[x][y + i * 8] * scale);
    }
}

// ---------- transpose V: qkv[B*S, 3072] cols 2048.. -> vt [B,H,DH,S] bf16 ----------
__global__ void transpose_v(const u16* __restrict__ qkv, u16* __restrict__ vt) {
    __shared__ u16 t[32][33];
    int bh = blockIdx.z; int b = bh >> 4, h = bh & 15;
    int s0 = blockIdx.x * 32, d0 = blockIdx.y * 32;
    int x = threadIdx.x, y = threadIdx.y;  // 32x8
#pragma unroll
    for (int i = 0; i < 4; ++i)
        t[y + i * 8][x] =
            qkv[(size_t)(b * S_ + s0 + y + i * 8) * QKVS + 2048 + h * DH_ + d0 + x];
    __syncthreads();
#pragma unroll
    for (int i = 0; i < 4; ++i)
        vt[((size_t)bh * DH_ + d0 + y + i * 8) * S_ + s0 + x] = t[x][y + i * 8];
}

// ---------- generic bf16 GEMM: C[M,N] = A[M,K] @ Bt[N,K]^T (+bias)(+relu) ----------
// 128x128 tile, 256 threads (4 waves in 2x2 of 64x64), BK=32, mfma 16x16x32.
// Staging via global_load_lds width=16.
__global__ __launch_bounds__(256) void gemm_bt(const u16* __restrict__ A,
                                               const u16* __restrict__ Bt,
                                               const float* __restrict__ bias,
                                               float* __restrict__ outF,
                                               u16* __restrict__ outB,
                                               int M, int N, int K, int relu) {
    __shared__ __align__(16) u16 sA[128 * 32];
    __shared__ __align__(16) u16 sB[128 * 32];

    int tid = threadIdx.x;
    int w = tid >> 6, lane = tid & 63, quad = lane >> 4, l = lane & 15;
    int wr = w >> 1, wc = w & 1;
    int bM = blockIdx.y, bN = blockIdx.x;

    floatx4 acc[4][4];
#pragma unroll
    for (int i = 0; i < 4; ++i)
#pragma unroll
        for (int j = 0; j < 4; ++j) acc[i][j] = (floatx4){0.f, 0.f, 0.f, 0.f};

    int r0 = lane >> 2;            // 0..15 row within wave's 16-row slab
    int c0 = (lane & 3) * 8;       // k-chunk (u16)

    for (int kk = 0; kk < K; kk += 32) {
#pragma unroll
        for (int hh = 0; hh < 2; ++hh) {
            int row = hh * 64 + w * 16 + r0;
            u16* lbase_a = &sA[(hh * 64 + w * 16) * 32];  // wave-uniform
            u16* lbase_b = &sB[(hh * 64 + w * 16) * 32];
            gl_lds16(&A[(size_t)(bM * 128 + row) * K + kk + c0], lbase_a);
            gl_lds16(&Bt[(size_t)(bN * 128 + row) * K + kk + c0], lbase_b);
        }
        __syncthreads();

        short8 af[4], bfr[4];
#pragma unroll
        for (int mt = 0; mt < 4; ++mt) {
            int m = wr * 64 + mt * 16 + l;
            af[mt] = *(const short8*)&sA[m * 32 + quad * 8];
        }
#pragma unroll
        for (int nt = 0; nt < 4; ++nt) {
            int n = wc * 64 + nt * 16 + l;
            bfr[nt] = *(const short8*)&sB[n * 32 + quad * 8];
        }
#pragma unroll
        for (int mt = 0; mt < 4; ++mt)
#pragma unroll
            for (int nt = 0; nt < 4; ++nt)
                acc[mt][nt] = mfma16(af[mt], bfr[nt], acc[mt][nt]);
        __syncthreads();
    }

    // epilogue
#pragma unroll
    for (int nt = 0; nt < 4; ++nt) {
        int colg = bN * 128 + wc * 64 + nt * 16 + l;
        float bv = bias ? bias[colg] : 0.f;
#pragma unroll
        for (int mt = 0; mt < 4; ++mt) {
#pragma unroll
            for (int r = 0; r < 4; ++r) {
                int rowg = bM * 128 + wr * 64 + mt * 16 + quad * 4 + r;
                float v = acc[mt][nt][r] + bv;
                if (relu) v = fmaxf(v, 0.f);
                size_t idx = (size_t)rowg * N + colg;
                if (outF) outF[idx] = v;
                if (outB) outB[idx] = f2b(v);
            }
        }
    }
}

// ---------- flash attention v4: no-max softmax, batched S-MFMAs (ILP),
// cross-iteration double-buffered P (PV reads previous iteration's P),
// K reload issued before the exp2 block. Q/K read from fused qkv (stride 3072).
// One block = (b,h) x 128 q-rows, 4 waves x 32 q-rows. grid: (S/128, B*H).
#define PSTR 72              // P row stride in bf16 (64 keys + 8 pad)
#define PBUF (32 * PSTR)     // one wave's P tile
__global__ __launch_bounds__(256) void attn_kernel(const u16* __restrict__ qkv,
                                                   const u16* __restrict__ vt,
                                                   u16* __restrict__ ctx) {
    __shared__ __align__(16) u16 Ps[8 * PBUF];  // 36.9 KB: [buf][wave][32][PSTR]

    int bh = blockIdx.y; int b = bh >> 4, h = bh & 15;
    int tid = threadIdx.x;
    int w = tid >> 6, lane = tid & 63, quad = lane >> 4, l = lane & 15;
    int qw = blockIdx.x * 128 + w * 32;  // this wave's first q-row
    u16* Pbase = &Ps[w * PBUF];

    // Q fragments, B-operand: B[n = l][k = quad*8+j], kept in registers
    short8 qf[2][2];
#pragma unroll
    for (int nt = 0; nt < 2; ++nt)
#pragma unroll
        for (int kf = 0; kf < 2; ++kf)
            qf[nt][kf] = *(const short8*)(qkv +
                (size_t)(b * S_ + qw + nt * 16 + l) * QKVS + h * DH_ + kf * 32 + quad * 8);

    float lrp0 = 0.f, lrp1 = 0.f;  // per-lane partial denominators
    floatx4 O[2][4];
#pragma unroll
    for (int i = 0; i < 2; ++i)
#pragma unroll
        for (int j = 0; j < 4; ++j) O[i][j] = (floatx4){0.f, 0.f, 0.f, 0.f};

    // persistent row pointers (strength-reduced addressing)
    const u16* kp[4];  // K rows mt*16+l (qkv cols 1024..2047), advance 64*QKVS/tile
    const u16* vp[4];  // V^T rows nd*16+l, advance 64/tile
#pragma unroll
    for (int mt = 0; mt < 4; ++mt)
        kp[mt] = qkv + (size_t)(b * S_ + mt * 16 + l) * QKVS + 1024 + h * DH_ + quad * 8;
#pragma unroll
    for (int nd = 0; nd < 4; ++nd)
        vp[nd] = vt + ((size_t)bh * DH_ + nd * 16 + l) * S_ + quad * 8;

    short8 kc[4][2];
    auto kload = [&]() {   // load current kp tile into kc, advance
#pragma unroll
        for (int mt = 0; mt < 4; ++mt) {
            kc[mt][0] = *(const short8*)kp[mt];
            kc[mt][1] = *(const short8*)(kp[mt] + 32);
            kp[mt] += 64 * QKVS;
        }
    };

    // sphase: batched S^T MFMAs from kc, issue next-K reload, then exp2+pack -> Pw
    auto sphase = [&](u16* Pw) {
        floatx4 s[4][2];
#pragma unroll
        for (int mt = 0; mt < 4; ++mt)
#pragma unroll
            for (int nt = 0; nt < 2; ++nt) {
                floatx4 c = (floatx4){0.f, 0.f, 0.f, 0.f};
                c = mfma16(kc[mt][0], qf[nt][0], c);
                c = mfma16(kc[mt][1], qf[nt][1], c);
                s[mt][nt] = c;
            }
        kload();  // next K tile in flight during exp2 (may overrun by 1 tile; lands in ws)
#pragma unroll
        for (int mt = 0; mt < 4; ++mt) {
            float e0 = exp2f_hw(s[mt][0][0]), e1 = exp2f_hw(s[mt][0][1]);
            float e2 = exp2f_hw(s[mt][0][2]), e3 = exp2f_hw(s[mt][0][3]);
            lrp0 += (e0 + e1) + (e2 + e3);
            uint2 pk0; pk0.x = pkbf(e0, e1); pk0.y = pkbf(e2, e3);
            *(uint2*)&Pw[l * PSTR + mt * 16 + quad * 4] = pk0;
            float f0 = exp2f_hw(s[mt][1][0]), f1 = exp2f_hw(s[mt][1][1]);
            float f2 = exp2f_hw(s[mt][1][2]), f3 = exp2f_hw(s[mt][1][3]);
            lrp1 += (f0 + f1) + (f2 + f3);
            uint2 pk1; pk1.x = pkbf(f0, f1); pk1.y = pkbf(f2, f3);
            *(uint2*)&Pw[(16 + l) * PSTR + mt * 16 + quad * 4] = pk1;
        }
    };

    kload();          // K(0) -> kc
    sphase(Pbase);    // P(0) -> buf0; kc now holds K(1)

    for (int kt = 0; kt < S_ / 64; ++kt) {
        u16* Pr = Pbase + (kt & 1) * (4 * PBUF);
        u16* Pw = Pbase + ((kt + 1) & 1) * (4 * PBUF);

        // P(kt) fragments (written last iteration) — LDS reads issued at top
        short8 pa[2][2];
#pragma unroll
        for (int mo = 0; mo < 2; ++mo)
#pragma unroll
            for (int kf = 0; kf < 2; ++kf)
                pa[mo][kf] = *(const short8*)&Pr[(mo * 16 + l) * PSTR + kf * 32 + quad * 8];

        // V(kt) fragments — global loads issued early
        short8 vf[4][2];
#pragma unroll
        for (int nd = 0; nd < 4; ++nd) {
            vf[nd][0] = *(const short8*)vp[nd];
            vf[nd][1] = *(const short8*)(vp[nd] + 32);
            vp[nd] += 64;
        }

        if (kt < S_ / 64 - 1) sphase(Pw);  // S(kt+1) -> other buffer

        // O += P(kt) @ V(kt)
#pragma unroll
        for (int kf = 0; kf < 2; ++kf)
#pragma unroll
            for (int nd = 0; nd < 4; ++nd)
#pragma unroll
                for (int mo = 0; mo < 2; ++mo)
                    O[mo][nd] = mfma16(pa[mo][kf], vf[nd][kf], O[mo][nd]);
    }

    // ---- epilogue: reduce lr across quads, O /= lsum, store bf16 ----
    lrp0 += __shfl_xor(lrp0, 16); lrp0 += __shfl_xor(lrp0, 32);
    lrp1 += __shfl_xor(lrp1, 16); lrp1 += __shfl_xor(lrp1, 32);
    float lrv[2] = {lrp0, lrp1};
#pragma unroll
    for (int mo = 0; mo < 2; ++mo) {
        float invl = 1.0f / lrv[mo];
        float i0 = __shfl(invl, quad * 4 + 0);
        float i1 = __shfl(invl, quad * 4 + 1);
        float i2 = __shfl(invl, quad * 4 + 2);
        float i3 = __shfl(invl, quad * 4 + 3);
#pragma unroll
        for (int nd = 0; nd < 4; ++nd) {
            size_t base = (size_t)(b * S_ + qw + mo * 16 + quad * 4) * D_ + h * DH_ + nd * 16 + l;
            ctx[base]          = f2b(O[mo][nd][0] * i0);
            ctx[base + D_]     = f2b(O[mo][nd][1] * i1);
            ctx[base + 2 * D_] = f2b(O[mo][nd][2] * i2);
            ctx[base + 3 * D_] = f2b(O[mo][nd][3] * i3);
        }
    }
}

// ---------- fused add + layernorm (one row of 1024 per block) ----------
__global__ __launch_bounds__(256) void add_ln(const float* __restrict__ a,
                                              const float* __restrict__ b,
                                              const float* __restrict__ g,
                                              const float* __restrict__ be,
                                              float* __restrict__ outF,
                                              u16* __restrict__ outB) {
    int row = blockIdx.x, tid = threadIdx.x;
    size_t base = (size_t)row * D_;
    float4 va = ((const float4*)(a + base))[tid];
    float4 vb = ((const float4*)(b + base))[tid];
    float x0 = va.x + vb.x, x1 = va.y + vb.y, x2 = va.z + vb.z, x3 = va.w + vb.w;
    float s1 = x0 + x1 + x2 + x3;
    float s2 = x0 * x0 + x1 * x1 + x2 * x2 + x3 * x3;
#pragma unroll
    for (int off = 32; off; off >>= 1) {
        s1 += __shfl_xor(s1, off);
        s2 += __shfl_xor(s2, off);
    }
    __shared__ float r1[4], r2[4];
    int w = tid >> 6, lane = tid & 63;
    if (lane == 0) { r1[w] = s1; r2[w] = s2; }
    __syncthreads();
    s1 = r1[0] + r1[1] + r1[2] + r1[3];
    s2 = r2[0] + r2[1] + r2[2] + r2[3];
    float mean = s1 * (1.0f / D_);
    float var = s2 * (1.0f / D_) - mean * mean;
    float inv = rsqrtf(var + 1e-6f);
    float4 vg = ((const float4*)g)[tid];
    float4 vbe = ((const float4*)be)[tid];
    float o0 = (x0 - mean) * inv * vg.x + vbe.x;
    float o1 = (x1 - mean) * inv * vg.y + vbe.y;
    float o2 = (x2 - mean) * inv * vg.z + vbe.z;
    float o3 = (x3 - mean) * inv * vg.w + vbe.w;
    float4 o; o.x = o0; o.y = o1; o.z = o2; o.w = o3;
    ((float4*)(outF + base))[tid] = o;
    if (outB) {
        ushort4 u;
        u.x = f2b(o0); u.y = f2b(o1); u.z = f2b(o2); u.w = f2b(o3);
        ((ushort4*)(outB + base))[tid] = u;
    }
}

extern "C" void kernel_launch(void* const* d_in, const int* in_sizes, int n_in,
                              void* d_out, int out_size, void* d_ws, size_t ws_size,
                              hipStream_t stream) {
    const float* x   = (const float*)d_in[0];
    const float* wq  = (const float*)d_in[1];
    const float* bq  = (const float*)d_in[2];
    const float* wk  = (const float*)d_in[3];
    const float* bk  = (const float*)d_in[4];
    const float* wv  = (const float*)d_in[5];
    const float* bv  = (const float*)d_in[6];
    const float* wo  = (const float*)d_in[7];
    const float* bo  = (const float*)d_in[8];
    const float* w1  = (const float*)d_in[9];
    const float* b1  = (const float*)d_in[10];
    const float* w2  = (const float*)d_in[11];
    const float* b2  = (const float*)d_in[12];
    const float* g1  = (const float*)d_in[13];
    const float* be1 = (const float*)d_in[14];
    const float* g2  = (const float*)d_in[15];
    const float* be2 = (const float*)d_in[16];
    float* out = (float*)d_out;
    char* ws = (char*)d_ws;
    const size_t MB = 1u << 20;

    // layout (185 MB total, with aliasing):
    u16* xb      = (u16*)(ws + 0);        // 16 MB (dead after QKV gemm)
    u16* wqkvT   = (u16*)(ws + 16 * MB);  // 6 MB [wq^T*QSCALE | wk^T | wv^T]
    u16* woT     = (u16*)(ws + 22 * MB);  // 2 MB
    u16* w1T     = (u16*)(ws + 24 * MB);  // 8 MB
    u16* w2T     = (u16*)(ws + 32 * MB);  // 8 MB
    float* qkvb  = (float*)(ws + 40 * MB);// 12 KB
    u16* qkv     = (u16*)(ws + 41 * MB);  // 48 MB (dead after attn)
    u16* vtb     = (u16*)(ws + 89 * MB);  // 16 MB (dead after attn)
    u16* ctxb    = (u16*)(ws + 105 * MB); // 16 MB
    float* attn_out = (float*)(ws + 121 * MB); // 32 MB (dead after add_ln1)
    float* out1     = (float*)(ws + 153 * MB); // 32 MB
    u16* out1b   = (u16*)(ws + 0);        // 16 MB, aliases dead xb
    u16* hidden  = (u16*)(ws + 41 * MB);  // 64 MB, aliases dead qkv+vtb
    float* ffn2out = (float*)(ws + 121 * MB); // aliases dead attn_out

    dim3 tb(32, 8);

    // prep: casts + weight transposes (wq pre-scaled by QSCALE = log2(e)/8)
    cast_b<<<8192, 256, 0, stream>>>(x, xb, (B_ * S_ * D_) / 4);
    transpose_cast<<<dim3(32, 32), tb, 0, stream>>>(wq, wqkvT, D_, D_, QSCALE);
    transpose_cast<<<dim3(32, 32), tb, 0, stream>>>(wk, wqkvT + 1024 * 1024, D_, D_, 1.0f);
    transpose_cast<<<dim3(32, 32), tb, 0, stream>>>(wv, wqkvT + 2048 * 1024, D_, D_, 1.0f);
    transpose_cast<<<dim3(32, 32), tb, 0, stream>>>(wo, woT, D_, D_, 1.0f);
    transpose_cast<<<dim3(128, 32), tb, 0, stream>>>(w1, w1T, D_, F_, 1.0f);
    transpose_cast<<<dim3(32, 128), tb, 0, stream>>>(w2, w2T, F_, D_, 1.0f);
    concat_bias<<<12, 256, 0, stream>>>(bq, bk, bv, qkvb);

    // fused QKV projection: [8192,1024] @ [3072,1024]^T -> qkv [8192,3072]
    gemm_bt<<<dim3(24, 64), 256, 0, stream>>>(xb, wqkvT, qkvb, nullptr, qkv,
                                              B_ * S_, QKVS, D_, 0);
    transpose_v<<<dim3(S_ / 32, DH_ / 32, B_ * H_), tb, 0, stream>>>(qkv, vtb);

    // attention (flash-style, cross-iteration P pipeline)
    attn_kernel<<<dim3(S_ / 128, B_ * H_), 256, 0, stream>>>(qkv, vtb, ctxb);

    // output projection (fp32 out, residual+LN done separately)
    gemm_bt<<<dim3(8, 64), 256, 0, stream>>>(ctxb, woT, bo, attn_out, nullptr,
                                             B_ * S_, D_, D_, 0);
    add_ln<<<B_ * S_, 256, 0, stream>>>(x, attn_out, g1, be1, out1, out1b);

    // FFN
    gemm_bt<<<dim3(32, 64), 256, 0, stream>>>(out1b, w1T, b1, nullptr, hidden,
                                              B_ * S_, F_, D_, 1);
    gemm_bt<<<dim3(8, 64), 256, 0, stream>>>(hidden, w2T, b2, ffn2out, nullptr,
                                             B_ * S_, D_, F_, 0);
    add_ln<<<B_ * S_, 256, 0, stream>>>(out1, ffn2out, g2, be2, out, nullptr);
}

// Round 7
// 651.776 us; speedup vs baseline: 1.3041x; 1.1918x over previous
//
#include <hip/hip_runtime.h>

typedef unsigned short u16;
typedef unsigned int u32;

typedef __attribute__((ext_vector_type(8))) short short8;
typedef __attribute__((ext_vector_type(4))) float floatx4;

// ---------- bf16 helpers ----------
static __device__ __forceinline__ u16 f2b(float f) {
    union { float f; u32 i; } v; v.f = f;
    u32 r = v.i + 0x7fffu + ((v.i >> 16) & 1u);
    return (u16)(r >> 16);
}
// pack two floats to bf16x2 dword (round-half-up)
static __device__ __forceinline__ u32 pkbf(float a, float b) {
    u32 ia = __float_as_uint(a) + 0x8000u;
    u32 ib = __float_as_uint(b) + 0x8000u;
    return (ia >> 16) | (ib & 0xffff0000u);
}
// 2^x via v_exp_f32
static __device__ __forceinline__ float exp2f_hw(float x) {
    return __builtin_amdgcn_exp2f(x);
}

static __device__ __forceinline__ floatx4 mfma16(short8 a, short8 b, floatx4 c) {
    return __builtin_amdgcn_mfma_f32_16x16x32_bf16(a, b, c, 0, 0, 0);
}

// async global->LDS, 16B per lane; LDS dest must be wave-uniform base (HW adds lane*16)
typedef __attribute__((address_space(1))) const void gas_void;
typedef __attribute__((address_space(3))) void las_void;
static __device__ __forceinline__ void gl_lds16(const void* g, void* l) {
    __builtin_amdgcn_global_load_lds((gas_void*)g, (las_void*)l, 16, 0, 0);
}

#define B_ 4
#define S_ 2048
#define D_ 1024
#define H_ 16
#define DH_ 64
#define F_ 4096
#define QKVS 3072   // row stride of fused qkv output

// (1/8) * log2(e), folded into wq/bq so logits come out in exp2 domain
#define QSCALE 0.18033688011112042f

// ---------- cast fp32 -> bf16, 4 elems/thread ----------
__global__ __launch_bounds__(256) void cast_b(const float* __restrict__ in,
                                              u16* __restrict__ out, int n4) {
    int id = blockIdx.x * 256 + threadIdx.x;
    if (id < n4) {
        float4 v = ((const float4*)in)[id];
        ushort4 u;
        u.x = f2b(v.x); u.y = f2b(v.y); u.z = f2b(v.z); u.w = f2b(v.w);
        ((ushort4*)out)[id] = u;
    }
}

// ---------- concat + scale bias: [bq*QSCALE | bk | bv] -> 3072 floats ----------
__global__ __launch_bounds__(256) void concat_bias(const float* __restrict__ bq,
                                                   const float* __restrict__ bk,
                                                   const float* __restrict__ bv,
                                                   float* __restrict__ o) {
    int i = blockIdx.x * 256 + threadIdx.x;
    float v;
    if (i < 1024) v = bq[i] * QSCALE;
    else if (i < 2048) v = bk[i - 1024];
    else v = bv[i - 2048];
    o[i] = v;
}

// ---------- transpose + cast + scale: in [R x C] fp32 -> out [C x R] bf16 ----------
__global__ void transpose_cast(const float* __restrict__ in, u16* __restrict__ out,
                               int R, int C, float scale) {
    __shared__ float t[32][33];
    int bx = blockIdx.x;  // over C
    int by = blockIdx.y;  // over R
    int x = threadIdx.x, y = threadIdx.y;  // 32x8
#pragma unroll
    for (int i = 0; i < 4; ++i) {
        int r = by * 32 + y + i * 8;
        t[y + i * 8][x] = in[(size_t)r * C + bx * 32 + x];
    }
    __syncthreads();
#pragma unroll
    for (int i = 0; i < 4; ++i) {
        int c = bx * 32 + y + i * 8;
        out[(size_t)c * R + by * 32 + x] = f2b(t[x][y + i * 8] * scale);
    }
}

// ---------- transpose V: qkv[B*S, 3072] cols 2048.. -> vt [B,H,DH,S] bf16 ----------
__global__ void transpose_v(const u16* __restrict__ qkv, u16* __restrict__ vt) {
    __shared__ u16 t[32][33];
    int bh = blockIdx.z; int b = bh >> 4, h = bh & 15;
    int s0 = blockIdx.x * 32, d0 = blockIdx.y * 32;
    int x = threadIdx.x, y = threadIdx.y;  // 32x8
#pragma unroll
    for (int i = 0; i < 4; ++i)
        t[y + i * 8][x] =
            qkv[(size_t)(b * S_ + s0 + y + i * 8) * QKVS + 2048 + h * DH_ + d0 + x];
    __syncthreads();
#pragma unroll
    for (int i = 0; i < 4; ++i)
        vt[((size_t)bh * DH_ + d0 + y + i * 8) * S_ + s0 + x] = t[x][y + i * 8];
}

// ---------- generic bf16 GEMM: C[M,N] = A[M,K] @ Bt[N,K]^T (+bias)(+relu) ----------
// 128x128 tile, 256 threads (4 waves in 2x2 of 64x64), BK=32, mfma 16x16x32.
__global__ __launch_bounds__(256) void gemm_bt(const u16* __restrict__ A,
                                               const u16* __restrict__ Bt,
                                               const float* __restrict__ bias,
                                               float* __restrict__ outF,
                                               u16* __restrict__ outB,
                                               int M, int N, int K, int relu) {
    __shared__ __align__(16) u16 sA[128 * 32];
    __shared__ __align__(16) u16 sB[128 * 32];

    int tid = threadIdx.x;
    int w = tid >> 6, lane = tid & 63, quad = lane >> 4, l = lane & 15;
    int wr = w >> 1, wc = w & 1;
    int bM = blockIdx.y, bN = blockIdx.x;

    floatx4 acc[4][4];
#pragma unroll
    for (int i = 0; i < 4; ++i)
#pragma unroll
        for (int j = 0; j < 4; ++j) acc[i][j] = (floatx4){0.f, 0.f, 0.f, 0.f};

    int r0 = lane >> 2;            // 0..15 row within wave's 16-row slab
    int c0 = (lane & 3) * 8;       // k-chunk (u16)

    for (int kk = 0; kk < K; kk += 32) {
#pragma unroll
        for (int hh = 0; hh < 2; ++hh) {
            int row = hh * 64 + w * 16 + r0;
            u16* lbase_a = &sA[(hh * 64 + w * 16) * 32];  // wave-uniform
            u16* lbase_b = &sB[(hh * 64 + w * 16) * 32];
            gl_lds16(&A[(size_t)(bM * 128 + row) * K + kk + c0], lbase_a);
            gl_lds16(&Bt[(size_t)(bN * 128 + row) * K + kk + c0], lbase_b);
        }
        __syncthreads();

        short8 af[4], bfr[4];
#pragma unroll
        for (int mt = 0; mt < 4; ++mt) {
            int m = wr * 64 + mt * 16 + l;
            af[mt] = *(const short8*)&sA[m * 32 + quad * 8];
        }
#pragma unroll
        for (int nt = 0; nt < 4; ++nt) {
            int n = wc * 64 + nt * 16 + l;
            bfr[nt] = *(const short8*)&sB[n * 32 + quad * 8];
        }
#pragma unroll
        for (int mt = 0; mt < 4; ++mt)
#pragma unroll
            for (int nt = 0; nt < 4; ++nt)
                acc[mt][nt] = mfma16(af[mt], bfr[nt], acc[mt][nt]);
        __syncthreads();
    }

    // epilogue
#pragma unroll
    for (int nt = 0; nt < 4; ++nt) {
        int colg = bN * 128 + wc * 64 + nt * 16 + l;
        float bv = bias ? bias[colg] : 0.f;
#pragma unroll
        for (int mt = 0; mt < 4; ++mt) {
#pragma unroll
            for (int r = 0; r < 4; ++r) {
                int rowg = bM * 128 + wr * 64 + mt * 16 + quad * 4 + r;
                float v = acc[mt][nt][r] + bv;
                if (relu) v = fmaxf(v, 0.f);
                size_t idx = (size_t)rowg * N + colg;
                if (outF) outF[idx] = v;
                if (outB) outB[idx] = f2b(v);
            }
        }
    }
}

// ---------- flash attention v5: cooperative LDS staging of K/V (global_load_lds,
// double-buffered, one barrier/iter) with 16B-granular XOR swizzle
// (LDS(row,cb) = G(row, cb ^ (row&7))) so lane-contiguous DMA + conflict-free
// ds_read_b128 coexist. No-max softmax (Q pre-scaled by QSCALE -> P = 2^s).
// One block = (b,h) x 128 q-rows, 4 waves x 32 q-rows.
// grid: (B*H, S/128) -> all q-tiles of one (b,h) on the same XCD (L2 locality).
#define PSTR 72              // P row stride in bf16 (64 keys + 8 pad)
__global__ __launch_bounds__(256) void attn_kernel(const u16* __restrict__ qkv,
                                                   const u16* __restrict__ vt,
                                                   u16* __restrict__ ctx) {
    __shared__ __align__(16) u16 Kb[2][64 * 64];   // 16 KB
    __shared__ __align__(16) u16 Vb[2][64 * 64];   // 16 KB
    __shared__ __align__(16) u16 Ps[4 * 32 * PSTR];  // 18 KB, wave-private

    int bh = blockIdx.x; int b = bh >> 4, h = bh & 15;
    int tid = threadIdx.x;
    int w = tid >> 6, lane = tid & 63, quad = lane >> 4, l = lane & 15;
    int qw = blockIdx.y * 128 + w * 32;  // this wave's first q-row
    u16* P = &Ps[w * 32 * PSTR];

    // staging coords: lane covers (row = wbase + i*8 + r, colblk = c), fetching
    // global colblk (c ^ r) -> LDS XOR swizzle with key row&7
    int r = lane >> 3, c = lane & 7;
    int cs = ((c ^ r) << 3);
    const u16* gK0 = qkv + (size_t)(b * S_ + w * 16 + r) * QKVS + 1024 + h * DH_ + cs;
    const u16* gK1 = gK0 + (size_t)8 * QKVS;
    const u16* gV0 = vt + (size_t)(bh * DH_ + w * 16 + r) * S_ + cs;
    const u16* gV1 = gV0 + (size_t)8 * S_;

    auto stage = [&](int bb) {
        u16* lk = &Kb[bb][w * 16 * 64];
        u16* lv = &Vb[bb][w * 16 * 64];
        gl_lds16(gK0, lk);
        gl_lds16(gK1, lk + 8 * 64);
        gl_lds16(gV0, lv);
        gl_lds16(gV1, lv + 8 * 64);
        gK0 += (size_t)64 * QKVS; gK1 += (size_t)64 * QKVS;
        gV0 += 64; gV1 += 64;
    };

    // Q fragments, B-operand: B[n = l][k = quad*8+j], kept in registers
    short8 qf[2][2];
#pragma unroll
    for (int nt = 0; nt < 2; ++nt)
#pragma unroll
        for (int kf = 0; kf < 2; ++kf)
            qf[nt][kf] = *(const short8*)(qkv +
                (size_t)(b * S_ + qw + nt * 16 + l) * QKVS + h * DH_ + kf * 32 + quad * 8);

    float lrp0 = 0.f, lrp1 = 0.f;  // per-lane partial denominators
    floatx4 O[2][4];
#pragma unroll
    for (int i = 0; i < 2; ++i)
#pragma unroll
        for (int j = 0; j < 4; ++j) O[i][j] = (floatx4){0.f, 0.f, 0.f, 0.f};

    // fragment-read swizzled col chunks: cq = kf*4+quad -> cb = cq ^ (l&7)
    int l7 = l & 7;
    int cb0 = ((quad ^ l7) << 3);   // kf=0 chunk (elems); kf=1 chunk = cb0 ^ 32 elems... (cq|4)^l7 = (quad^l7)^4 -> +/-32 elems
    int fb = l * 64;                // frag row base (elems)

    stage(0);
    __syncthreads();

    const int NT = S_ / 64;
    for (int kt = 0; kt < NT; ++kt) {
        int cur = kt & 1;
        if (kt + 1 < NT) stage(cur ^ 1);

        // ---- S^T tiles: A = K rows (m = mt*16+l) from LDS, B = Q regs ----
        const u16* Kc = Kb[cur];
        floatx4 s[4][2];
#pragma unroll
        for (int mt = 0; mt < 4; ++mt) {
            short8 ka0 = *(const short8*)&Kc[mt * 1024 + fb + cb0];
            short8 ka1 = *(const short8*)&Kc[mt * 1024 + fb + (cb0 ^ 32)];
#pragma unroll
            for (int nt = 0; nt < 2; ++nt) {
                floatx4 cacc = (floatx4){0.f, 0.f, 0.f, 0.f};
                cacc = mfma16(ka0, qf[nt][0], cacc);
                cacc = mfma16(ka1, qf[nt][1], cacc);
                s[mt][nt] = cacc;
            }
        }

        // ---- softmax-lite: e = 2^s, per-lane partial sums, pack to P ----
#pragma unroll
        for (int mt = 0; mt < 4; ++mt) {
            float e0 = exp2f_hw(s[mt][0][0]), e1 = exp2f_hw(s[mt][0][1]);
            float e2 = exp2f_hw(s[mt][0][2]), e3 = exp2f_hw(s[mt][0][3]);
            lrp0 += (e0 + e1) + (e2 + e3);
            uint2 pk0; pk0.x = pkbf(e0, e1); pk0.y = pkbf(e2, e3);
            *(uint2*)&P[l * PSTR + mt * 16 + quad * 4] = pk0;
            float f0 = exp2f_hw(s[mt][1][0]), f1 = exp2f_hw(s[mt][1][1]);
            float f2 = exp2f_hw(s[mt][1][2]), f3 = exp2f_hw(s[mt][1][3]);
            lrp1 += (f0 + f1) + (f2 + f3);
            uint2 pk1; pk1.x = pkbf(f0, f1); pk1.y = pkbf(f2, f3);
            *(uint2*)&P[(16 + l) * PSTR + mt * 16 + quad * 4] = pk1;
        }

        // ---- O += P @ V: A = P rows from LDS, B = V^T rows (n = nd*16+l) from LDS ----
        short8 pa[2][2];
#pragma unroll
        for (int mo = 0; mo < 2; ++mo)
#pragma unroll
            for (int kf = 0; kf < 2; ++kf)
                pa[mo][kf] = *(const short8*)&P[(mo * 16 + l) * PSTR + kf * 32 + quad * 8];

        const u16* Vc = Vb[cur];
#pragma unroll
        for (int nd = 0; nd < 4; ++nd) {
            short8 vb0 = *(const short8*)&Vc[nd * 1024 + fb + cb0];
            short8 vb1 = *(const short8*)&Vc[nd * 1024 + fb + (cb0 ^ 32)];
#pragma unroll
            for (int mo = 0; mo < 2; ++mo) {
                O[mo][nd] = mfma16(pa[mo][0], vb0, O[mo][nd]);
                O[mo][nd] = mfma16(pa[mo][1], vb1, O[mo][nd]);
            }
        }

        __syncthreads();  // drains gl_lds (vmcnt) + protects buffer swap
    }

    // ---- epilogue: reduce lr across quads, O /= lsum, store bf16 ----
    lrp0 += __shfl_xor(lrp0, 16); lrp0 += __shfl_xor(lrp0, 32);
    lrp1 += __shfl_xor(lrp1, 16); lrp1 += __shfl_xor(lrp1, 32);
    float lrv[2] = {lrp0, lrp1};
#pragma unroll
    for (int mo = 0; mo < 2; ++mo) {
        float invl = 1.0f / lrv[mo];
        float i0 = __shfl(invl, quad * 4 + 0);
        float i1 = __shfl(invl, quad * 4 + 1);
        float i2 = __shfl(invl, quad * 4 + 2);
        float i3 = __shfl(invl, quad * 4 + 3);
#pragma unroll
        for (int nd = 0; nd < 4; ++nd) {
            size_t base = (size_t)(b * S_ + qw + mo * 16 + quad * 4) * D_ + h * DH_ + nd * 16 + l;
            ctx[base]          = f2b(O[mo][nd][0] * i0);
            ctx[base + D_]     = f2b(O[mo][nd][1] * i1);
            ctx[base + 2 * D_] = f2b(O[mo][nd][2] * i2);
            ctx[base + 3 * D_] = f2b(O[mo][nd][3] * i3);
        }
    }
}

// ---------- fused add + layernorm (one row of 1024 per block) ----------
__global__ __launch_bounds__(256) void add_ln(const float* __restrict__ a,
                                              const float* __restrict__ b,
                                              const float* __restrict__ g,
                                              const float* __restrict__ be,
                                              float* __restrict__ outF,
                                              u16* __restrict__ outB) {
    int row = blockIdx.x, tid = threadIdx.x;
    size_t base = (size_t)row * D_;
    float4 va = ((const float4*)(a + base))[tid];
    float4 vb = ((const float4*)(b + base))[tid];
    float x0 = va.x + vb.x, x1 = va.y + vb.y, x2 = va.z + vb.z, x3 = va.w + vb.w;
    float s1 = x0 + x1 + x2 + x3;
    float s2 = x0 * x0 + x1 * x1 + x2 * x2 + x3 * x3;
#pragma unroll
    for (int off = 32; off; off >>= 1) {
        s1 += __shfl_xor(s1, off);
        s2 += __shfl_xor(s2, off);
    }
    __shared__ float r1[4], r2[4];
    int w = tid >> 6, lane = tid & 63;
    if (lane == 0) { r1[w] = s1; r2[w] = s2; }
    __syncthreads();
    s1 = r1[0] + r1[1] + r1[2] + r1[3];
    s2 = r2[0] + r2[1] + r2[2] + r2[3];
    float mean = s1 * (1.0f / D_);
    float var = s2 * (1.0f / D_) - mean * mean;
    float inv = rsqrtf(var + 1e-6f);
    float4 vg = ((const float4*)g)[tid];
    float4 vbe = ((const float4*)be)[tid];
    float o0 = (x0 - mean) * inv * vg.x + vbe.x;
    float o1 = (x1 - mean) * inv * vg.y + vbe.y;
    float o2 = (x2 - mean) * inv * vg.z + vbe.z;
    float o3 = (x3 - mean) * inv * vg.w + vbe.w;
    float4 o; o.x = o0; o.y = o1; o.z = o2; o.w = o3;
    ((float4*)(outF + base))[tid] = o;
    if (outB) {
        ushort4 u;
        u.x = f2b(o0); u.y = f2b(o1); u.z = f2b(o2); u.w = f2b(o3);
        ((ushort4*)(outB + base))[tid] = u;
    }
}

extern "C" void kernel_launch(void* const* d_in, const int* in_sizes, int n_in,
                              void* d_out, int out_size, void* d_ws, size_t ws_size,
                              hipStream_t stream) {
    const float* x   = (const float*)d_in[0];
    const float* wq  = (const float*)d_in[1];
    const float* bq  = (const float*)d_in[2];
    const float* wk  = (const float*)d_in[3];
    const float* bk  = (const float*)d_in[4];
    const float* wv  = (const float*)d_in[5];
    const float* bv  = (const float*)d_in[6];
    const float* wo  = (const float*)d_in[7];
    const float* bo  = (const float*)d_in[8];
    const float* w1  = (const float*)d_in[9];
    const float* b1  = (const float*)d_in[10];
    const float* w2  = (const float*)d_in[11];
    const float* b2  = (const float*)d_in[12];
    const float* g1  = (const float*)d_in[13];
    const float* be1 = (const float*)d_in[14];
    const float* g2  = (const float*)d_in[15];
    const float* be2 = (const float*)d_in[16];
    float* out = (float*)d_out;
    char* ws = (char*)d_ws;
    const size_t MB = 1u << 20;

    // layout (185 MB total, with aliasing):
    u16* xb      = (u16*)(ws + 0);        // 16 MB (dead after QKV gemm)
    u16* wqkvT   = (u16*)(ws + 16 * MB);  // 6 MB [wq^T*QSCALE | wk^T | wv^T]
    u16* woT     = (u16*)(ws + 22 * MB);  // 2 MB
    u16* w1T     = (u16*)(ws + 24 * MB);  // 8 MB
    u16* w2T     = (u16*)(ws + 32 * MB);  // 8 MB
    float* qkvb  = (float*)(ws + 40 * MB);// 12 KB
    u16* qkv     = (u16*)(ws + 41 * MB);  // 48 MB (dead after attn)
    u16* vtb     = (u16*)(ws + 89 * MB);  // 16 MB (dead after attn)
    u16* ctxb    = (u16*)(ws + 105 * MB); // 16 MB
    float* attn_out = (float*)(ws + 121 * MB); // 32 MB (dead after add_ln1)
    float* out1     = (float*)(ws + 153 * MB); // 32 MB
    u16* out1b   = (u16*)(ws + 0);        // 16 MB, aliases dead xb
    u16* hidden  = (u16*)(ws + 41 * MB);  // 64 MB, aliases dead qkv+vtb
    float* ffn2out = (float*)(ws + 121 * MB); // aliases dead attn_out

    dim3 tb(32, 8);

    // prep: casts + weight transposes (wq pre-scaled by QSCALE = log2(e)/8)
    cast_b<<<8192, 256, 0, stream>>>(x, xb, (B_ * S_ * D_) / 4);
    transpose_cast<<<dim3(32, 32), tb, 0, stream>>>(wq, wqkvT, D_, D_, QSCALE);
    transpose_cast<<<dim3(32, 32), tb, 0, stream>>>(wk, wqkvT + 1024 * 1024, D_, D_, 1.0f);
    transpose_cast<<<dim3(32, 32), tb, 0, stream>>>(wv, wqkvT + 2048 * 1024, D_, D_, 1.0f);
    transpose_cast<<<dim3(32, 32), tb, 0, stream>>>(wo, woT, D_, D_, 1.0f);
    transpose_cast<<<dim3(128, 32), tb, 0, stream>>>(w1, w1T, D_, F_, 1.0f);
    transpose_cast<<<dim3(32, 128), tb, 0, stream>>>(w2, w2T, F_, D_, 1.0f);
    concat_bias<<<12, 256, 0, stream>>>(bq, bk, bv, qkvb);

    // fused QKV projection: [8192,1024] @ [3072,1024]^T -> qkv [8192,3072]
    gemm_bt<<<dim3(24, 64), 256, 0, stream>>>(xb, wqkvT, qkvb, nullptr, qkv,
                                              B_ * S_, QKVS, D_, 0);
    transpose_v<<<dim3(S_ / 32, DH_ / 32, B_ * H_), tb, 0, stream>>>(qkv, vtb);

    // attention (flash-style, LDS-staged K/V, XCD-clustered per (b,h))
    attn_kernel<<<dim3(B_ * H_, S_ / 128), 256, 0, stream>>>(qkv, vtb, ctxb);

    // output projection (fp32 out, residual+LN done separately)
    gemm_bt<<<dim3(8, 64), 256, 0, stream>>>(ctxb, woT, bo, attn_out, nullptr,
                                             B_ * S_, D_, D_, 0);
    add_ln<<<B_ * S_, 256, 0, stream>>>(x, attn_out, g1, be1, out1, out1b);

    // FFN
    gemm_bt<<<dim3(32, 64), 256, 0, stream>>>(out1b, w1T, b1, nullptr, hidden,
                                              B_ * S_, F_, D_, 1);
    gemm_bt<<<dim3(8, 64), 256, 0, stream>>>(hidden, w2T, b2, ffn2out, nullptr,
                                             B_ * S_, D_, F_, 0);
    add_ln<<<B_ * S_, 256, 0, stream>>>(out1, ffn2out, g2, be2, out, nullptr);
}

// Round 8
// 586.472 us; speedup vs baseline: 1.4493x; 1.1114x over previous
//
#include <hip/hip_runtime.h>

typedef unsigned short u16;
typedef unsigned int u32;

typedef __attribute__((ext_vector_type(8))) short short8;
typedef __attribute__((ext_vector_type(4))) float floatx4;

// ---------- bf16 helpers ----------
static __device__ __forceinline__ u16 f2b(float f) {
    union { float f; u32 i; } v; v.f = f;
    u32 r = v.i + 0x7fffu + ((v.i >> 16) & 1u);
    return (u16)(r >> 16);
}
// pack two floats to bf16x2 dword (round-half-up)
static __device__ __forceinline__ u32 pkbf(float a, float b) {
    u32 ia = __float_as_uint(a) + 0x8000u;
    u32 ib = __float_as_uint(b) + 0x8000u;
    return (ia >> 16) | (ib & 0xffff0000u);
}
// 2^x via v_exp_f32
static __device__ __forceinline__ float exp2f_hw(float x) {
    return __builtin_amdgcn_exp2f(x);
}

static __device__ __forceinline__ floatx4 mfma16(short8 a, short8 b, floatx4 c) {
    return __builtin_amdgcn_mfma_f32_16x16x32_bf16(a, b, c, 0, 0, 0);
}

// async global->LDS, 16B per lane; LDS dest must be wave-uniform base (HW adds lane*16)
typedef __attribute__((address_space(1))) const void gas_void;
typedef __attribute__((address_space(3))) void las_void;
static __device__ __forceinline__ void gl_lds16(const void* g, void* l) {
    __builtin_amdgcn_global_load_lds((gas_void*)g, (las_void*)l, 16, 0, 0);
}

#define B_ 4
#define S_ 2048
#define D_ 1024
#define H_ 16
#define DH_ 64
#define F_ 4096
#define QKVS 3072   // row stride of fused qkv output

// (1/8) * log2(e), folded into wq/bq so logits come out in exp2 domain
#define QSCALE 0.18033688011112042f

// ---------- cast fp32 -> bf16, 4 elems/thread ----------
__global__ __launch_bounds__(256) void cast_b(const float* __restrict__ in,
                                              u16* __restrict__ out, int n4) {
    int id = blockIdx.x * 256 + threadIdx.x;
    if (id < n4) {
        float4 v = ((const float4*)in)[id];
        ushort4 u;
        u.x = f2b(v.x); u.y = f2b(v.y); u.z = f2b(v.z); u.w = f2b(v.w);
        ((ushort4*)out)[id] = u;
    }
}

// ---------- concat + scale bias: [bq*QSCALE | bk | bv] -> 3072 floats ----------
__global__ __launch_bounds__(256) void concat_bias(const float* __restrict__ bq,
                                                   const float* __restrict__ bk,
                                                   const float* __restrict__ bv,
                                                   float* __restrict__ o) {
    int i = blockIdx.x * 256 + threadIdx.x;
    float v;
    if (i < 1024) v = bq[i] * QSCALE;
    else if (i < 2048) v = bk[i - 1024];
    else v = bv[i - 2048];
    o[i] = v;
}

// ---------- transpose + cast + scale: in [R x C] fp32 -> out [C x R] bf16 ----------
__global__ void transpose_cast(const float* __restrict__ in, u16* __restrict__ out,
                               int R, int C, float scale) {
    __shared__ float t[32][33];
    int bx = blockIdx.x;  // over C
    int by = blockIdx.y;  // over R
    int x = threadIdx.x, y = threadIdx.y;  // 32x8
#pragma unroll
    for (int i = 0; i < 4; ++i) {
        int r = by * 32 + y + i * 8;
        t[y + i * 8][x] = in[(size_t)r * C + bx * 32 + x];
    }
    __syncthreads();
#pragma unroll
    for (int i = 0; i < 4; ++i) {
        int c = bx * 32 + y + i * 8;
        out[(size_t)c * R + by * 32 + x] = f2b(t[x][y + i * 8] * scale);
    }
}

// ---------- transpose V: qkv[B*S, 3072] cols 2048.. -> vt [B,H,DH,S] bf16 ----------
__global__ void transpose_v(const u16* __restrict__ qkv, u16* __restrict__ vt) {
    __shared__ u16 t[32][33];
    int bh = blockIdx.z; int b = bh >> 4, h = bh & 15;
    int s0 = blockIdx.x * 32, d0 = blockIdx.y * 32;
    int x = threadIdx.x, y = threadIdx.y;  // 32x8
#pragma unroll
    for (int i = 0; i < 4; ++i)
        t[y + i * 8][x] =
            qkv[(size_t)(b * S_ + s0 + y + i * 8) * QKVS + 2048 + h * DH_ + d0 + x];
    __syncthreads();
#pragma unroll
    for (int i = 0; i < 4; ++i)
        vt[((size_t)bh * DH_ + d0 + y + i * 8) * S_ + s0 + x] = t[x][y + i * 8];
}

// ---------- generic bf16 GEMM v2: C[M,N] = A[M,K] @ Bt[N,K]^T (+bias)(+relu) ----------
// 128x128 tile, 256 threads (4 waves in 2x2 of 64x64), BK=64 (32 MFMA/barrier),
// global_load_lds width=16 staging with 8-chunk XOR swizzle:
// LDS chunk c of row r holds global chunk c^(r&7) -> ds_read_b128 frags conflict-free.
__global__ __launch_bounds__(256) void gemm_bt(const u16* __restrict__ A,
                                               const u16* __restrict__ Bt,
                                               const float* __restrict__ bias,
                                               float* __restrict__ outF,
                                               u16* __restrict__ outB,
                                               int M, int N, int K, int relu) {
    __shared__ __align__(16) u16 sA[128 * 64];   // 16 KB
    __shared__ __align__(16) u16 sB[128 * 64];   // 16 KB

    int tid = threadIdx.x;
    int w = tid >> 6, lane = tid & 63, quad = lane >> 4, l = lane & 15;
    int wr = w >> 1, wc = w & 1;
    int bM = blockIdx.y, bN = blockIdx.x;

    floatx4 acc[4][4];
#pragma unroll
    for (int i = 0; i < 4; ++i)
#pragma unroll
        for (int j = 0; j < 4; ++j) acc[i][j] = (floatx4){0.f, 0.f, 0.f, 0.f};

    // staging coords: r = row within 8-row slab, c = LDS chunk; fetch global chunk c^r
    int r = lane >> 3;            // 0..7
    int c = lane & 7;             // 0..7
    int cg = ((c ^ r) << 3);      // global chunk offset in elems
    const u16* gA = &A[(size_t)(bM * 128 + r) * K + cg];
    const u16* gB = &Bt[(size_t)(bN * 128 + r) * K + cg];

    int l7 = l & 7;

    for (int kk = 0; kk < K; kk += 64) {
#pragma unroll
        for (int hh = 0; hh < 4; ++hh) {
            int rowbase = hh * 32 + w * 8;            // multiple of 8
            gl_lds16(gA + (size_t)rowbase * K + kk, &sA[rowbase * 64]);
            gl_lds16(gB + (size_t)rowbase * K + kk, &sB[rowbase * 64]);
        }
        __syncthreads();

#pragma unroll
        for (int kf = 0; kf < 2; ++kf) {
            int ch = ((kf * 4 + quad) ^ l7) << 3;     // swizzled chunk offset
            short8 af[4], bfr[4];
#pragma unroll
            for (int mt = 0; mt < 4; ++mt) {
                int m = wr * 64 + mt * 16 + l;        // m%8 == l%8
                af[mt] = *(const short8*)&sA[m * 64 + ch];
            }
#pragma unroll
            for (int nt = 0; nt < 4; ++nt) {
                int n = wc * 64 + nt * 16 + l;
                bfr[nt] = *(const short8*)&sB[n * 64 + ch];
            }
#pragma unroll
            for (int mt = 0; mt < 4; ++mt)
#pragma unroll
                for (int nt = 0; nt < 4; ++nt)
                    acc[mt][nt] = mfma16(af[mt], bfr[nt], acc[mt][nt]);
        }
        __syncthreads();
    }

    // epilogue
#pragma unroll
    for (int nt = 0; nt < 4; ++nt) {
        int colg = bN * 128 + wc * 64 + nt * 16 + l;
        float bv = bias ? bias[colg] : 0.f;
#pragma unroll
        for (int mt = 0; mt < 4; ++mt) {
#pragma unroll
            for (int rr = 0; rr < 4; ++rr) {
                int rowg = bM * 128 + wr * 64 + mt * 16 + quad * 4 + rr;
                float v = acc[mt][nt][rr] + bv;
                if (relu) v = fmaxf(v, 0.f);
                size_t idx = (size_t)rowg * N + colg;
                if (outF) outF[idx] = v;
                if (outB) outB[idx] = f2b(v);
            }
        }
    }
}

// ---------- flash attention v5: cooperative LDS staging of K/V (global_load_lds,
// double-buffered, one barrier/iter) with 16B-granular XOR swizzle
// (LDS(row,cb) = G(row, cb ^ (row&7))) so lane-contiguous DMA + conflict-free
// ds_read_b128 coexist. No-max softmax (Q pre-scaled by QSCALE -> P = 2^s).
// One block = (b,h) x 128 q-rows, 4 waves x 32 q-rows.
// grid: (B*H, S/128) -> all q-tiles of one (b,h) on the same XCD (L2 locality).
#define PSTR 72              // P row stride in bf16 (64 keys + 8 pad)
__global__ __launch_bounds__(256) void attn_kernel(const u16* __restrict__ qkv,
                                                   const u16* __restrict__ vt,
                                                   u16* __restrict__ ctx) {
    __shared__ __align__(16) u16 Kb[2][64 * 64];   // 16 KB
    __shared__ __align__(16) u16 Vb[2][64 * 64];   // 16 KB
    __shared__ __align__(16) u16 Ps[4 * 32 * PSTR];  // 18 KB, wave-private

    int bh = blockIdx.x; int b = bh >> 4, h = bh & 15;
    int tid = threadIdx.x;
    int w = tid >> 6, lane = tid & 63, quad = lane >> 4, l = lane & 15;
    int qw = blockIdx.y * 128 + w * 32;  // this wave's first q-row
    u16* P = &Ps[w * 32 * PSTR];

    // staging coords: lane covers (row = wbase + i*8 + r, colblk = c), fetching
    // global colblk (c ^ r) -> LDS XOR swizzle with key row&7
    int r = lane >> 3, c = lane & 7;
    int cs = ((c ^ r) << 3);
    const u16* gK0 = qkv + (size_t)(b * S_ + w * 16 + r) * QKVS + 1024 + h * DH_ + cs;
    const u16* gK1 = gK0 + (size_t)8 * QKVS;
    const u16* gV0 = vt + (size_t)(bh * DH_ + w * 16 + r) * S_ + cs;
    const u16* gV1 = gV0 + (size_t)8 * S_;

    auto stage = [&](int bb) {
        u16* lk = &Kb[bb][w * 16 * 64];
        u16* lv = &Vb[bb][w * 16 * 64];
        gl_lds16(gK0, lk);
        gl_lds16(gK1, lk + 8 * 64);
        gl_lds16(gV0, lv);
        gl_lds16(gV1, lv + 8 * 64);
        gK0 += (size_t)64 * QKVS; gK1 += (size_t)64 * QKVS;
        gV0 += 64; gV1 += 64;
    };

    // Q fragments, B-operand: B[n = l][k = quad*8+j], kept in registers
    short8 qf[2][2];
#pragma unroll
    for (int nt = 0; nt < 2; ++nt)
#pragma unroll
        for (int kf = 0; kf < 2; ++kf)
            qf[nt][kf] = *(const short8*)(qkv +
                (size_t)(b * S_ + qw + nt * 16 + l) * QKVS + h * DH_ + kf * 32 + quad * 8);

    float lrp0 = 0.f, lrp1 = 0.f;  // per-lane partial denominators
    floatx4 O[2][4];
#pragma unroll
    for (int i = 0; i < 2; ++i)
#pragma unroll
        for (int j = 0; j < 4; ++j) O[i][j] = (floatx4){0.f, 0.f, 0.f, 0.f};

    // fragment-read swizzled col chunks: cq = kf*4+quad -> cb = cq ^ (l&7)
    int l7 = l & 7;
    int cb0 = ((quad ^ l7) << 3);   // kf=0 chunk (elems); kf=1 chunk = cb0 ^ 32
    int fb = l * 64;                // frag row base (elems)

    stage(0);
    __syncthreads();

    const int NT = S_ / 64;
    for (int kt = 0; kt < NT; ++kt) {
        int cur = kt & 1;
        if (kt + 1 < NT) stage(cur ^ 1);

        // ---- S^T tiles: A = K rows (m = mt*16+l) from LDS, B = Q regs ----
        const u16* Kc = Kb[cur];
        floatx4 s[4][2];
#pragma unroll
        for (int mt = 0; mt < 4; ++mt) {
            short8 ka0 = *(const short8*)&Kc[mt * 1024 + fb + cb0];
            short8 ka1 = *(const short8*)&Kc[mt * 1024 + fb + (cb0 ^ 32)];
#pragma unroll
            for (int nt = 0; nt < 2; ++nt) {
                floatx4 cacc = (floatx4){0.f, 0.f, 0.f, 0.f};
                cacc = mfma16(ka0, qf[nt][0], cacc);
                cacc = mfma16(ka1, qf[nt][1], cacc);
                s[mt][nt] = cacc;
            }
        }

        // ---- softmax-lite: e = 2^s, per-lane partial sums, pack to P ----
#pragma unroll
        for (int mt = 0; mt < 4; ++mt) {
            float e0 = exp2f_hw(s[mt][0][0]), e1 = exp2f_hw(s[mt][0][1]);
            float e2 = exp2f_hw(s[mt][0][2]), e3 = exp2f_hw(s[mt][0][3]);
            lrp0 += (e0 + e1) + (e2 + e3);
            uint2 pk0; pk0.x = pkbf(e0, e1); pk0.y = pkbf(e2, e3);
            *(uint2*)&P[l * PSTR + mt * 16 + quad * 4] = pk0;
            float f0 = exp2f_hw(s[mt][1][0]), f1 = exp2f_hw(s[mt][1][1]);
            float f2 = exp2f_hw(s[mt][1][2]), f3 = exp2f_hw(s[mt][1][3]);
            lrp1 += (f0 + f1) + (f2 + f3);
            uint2 pk1; pk1.x = pkbf(f0, f1); pk1.y = pkbf(f2, f3);
            *(uint2*)&P[(16 + l) * PSTR + mt * 16 + quad * 4] = pk1;
        }

        // ---- O += P @ V: A = P rows from LDS, B = V^T rows (n = nd*16+l) from LDS ----
        short8 pa[2][2];
#pragma unroll
        for (int mo = 0; mo < 2; ++mo)
#pragma unroll
            for (int kf = 0; kf < 2; ++kf)
                pa[mo][kf] = *(const short8*)&P[(mo * 16 + l) * PSTR + kf * 32 + quad * 8];

        const u16* Vc = Vb[cur];
#pragma unroll
        for (int nd = 0; nd < 4; ++nd) {
            short8 vb0 = *(const short8*)&Vc[nd * 1024 + fb + cb0];
            short8 vb1 = *(const short8*)&Vc[nd * 1024 + fb + (cb0 ^ 32)];
#pragma unroll
            for (int mo = 0; mo < 2; ++mo) {
                O[mo][nd] = mfma16(pa[mo][0], vb0, O[mo][nd]);
                O[mo][nd] = mfma16(pa[mo][1], vb1, O[mo][nd]);
            }
        }

        __syncthreads();  // drains gl_lds (vmcnt) + protects buffer swap
    }

    // ---- epilogue: reduce lr across quads, O /= lsum, store bf16 ----
    lrp0 += __shfl_xor(lrp0, 16); lrp0 += __shfl_xor(lrp0, 32);
    lrp1 += __shfl_xor(lrp1, 16); lrp1 += __shfl_xor(lrp1, 32);
    float lrv[2] = {lrp0, lrp1};
#pragma unroll
    for (int mo = 0; mo < 2; ++mo) {
        float invl = 1.0f / lrv[mo];
        float i0 = __shfl(invl, quad * 4 + 0);
        float i1 = __shfl(invl, quad * 4 + 1);
        float i2 = __shfl(invl, quad * 4 + 2);
        float i3 = __shfl(invl, quad * 4 + 3);
#pragma unroll
        for (int nd = 0; nd < 4; ++nd) {
            size_t base = (size_t)(b * S_ + qw + mo * 16 + quad * 4) * D_ + h * DH_ + nd * 16 + l;
            ctx[base]          = f2b(O[mo][nd][0] * i0);
            ctx[base + D_]     = f2b(O[mo][nd][1] * i1);
            ctx[base + 2 * D_] = f2b(O[mo][nd][2] * i2);
            ctx[base + 3 * D_] = f2b(O[mo][nd][3] * i3);
        }
    }
}

// ---------- fused add + layernorm (one row of 1024 per block) ----------
__global__ __launch_bounds__(256) void add_ln(const float* __restrict__ a,
                                              const float* __restrict__ b,
                                              const float* __restrict__ g,
                                              const float* __restrict__ be,
                                              float* __restrict__ outF,
                                              u16* __restrict__ outB) {
    int row = blockIdx.x, tid = threadIdx.x;
    size_t base = (size_t)row * D_;
    float4 va = ((const float4*)(a + base))[tid];
    float4 vb = ((const float4*)(b + base))[tid];
    float x0 = va.x + vb.x, x1 = va.y + vb.y, x2 = va.z + vb.z, x3 = va.w + vb.w;
    float s1 = x0 + x1 + x2 + x3;
    float s2 = x0 * x0 + x1 * x1 + x2 * x2 + x3 * x3;
#pragma unroll
    for (int off = 32; off; off >>= 1) {
        s1 += __shfl_xor(s1, off);
        s2 += __shfl_xor(s2, off);
    }
    __shared__ float r1[4], r2[4];
    int w = tid >> 6, lane = tid & 63;
    if (lane == 0) { r1[w] = s1; r2[w] = s2; }
    __syncthreads();
    s1 = r1[0] + r1[1] + r1[2] + r1[3];
    s2 = r2[0] + r2[1] + r2[2] + r2[3];
    float mean = s1 * (1.0f / D_);
    float var = s2 * (1.0f / D_) - mean * mean;
    float inv = rsqrtf(var + 1e-6f);
    float4 vg = ((const float4*)g)[tid];
    float4 vbe = ((const float4*)be)[tid];
    float o0 = (x0 - mean) * inv * vg.x + vbe.x;
    float o1 = (x1 - mean) * inv * vg.y + vbe.y;
    float o2 = (x2 - mean) * inv * vg.z + vbe.z;
    float o3 = (x3 - mean) * inv * vg.w + vbe.w;
    float4 o; o.x = o0; o.y = o1; o.z = o2; o.w = o3;
    ((float4*)(outF + base))[tid] = o;
    if (outB) {
        ushort4 u;
        u.x = f2b(o0); u.y = f2b(o1); u.z = f2b(o2); u.w = f2b(o3);
        ((ushort4*)(outB + base))[tid] = u;
    }
}

extern "C" void kernel_launch(void* const* d_in, const int* in_sizes, int n_in,
                              void* d_out, int out_size, void* d_ws, size_t ws_size,
                              hipStream_t stream) {
    const float* x   = (const float*)d_in[0];
    const float* wq  = (const float*)d_in[1];
    const float* bq  = (const float*)d_in[2];
    const float* wk  = (const float*)d_in[3];
    const float* bk  = (const float*)d_in[4];
    const float* wv  = (const float*)d_in[5];
    const float* bv  = (const float*)d_in[6];
    const float* wo  = (const float*)d_in[7];
    const float* bo  = (const float*)d_in[8];
    const float* w1  = (const float*)d_in[9];
    const float* b1  = (const float*)d_in[10];
    const float* w2  = (const float*)d_in[11];
    const float* b2  = (const float*)d_in[12];
    const float* g1  = (const float*)d_in[13];
    const float* be1 = (const float*)d_in[14];
    const float* g2  = (const float*)d_in[15];
    const float* be2 = (const float*)d_in[16];
    float* out = (float*)d_out;
    char* ws = (char*)d_ws;
    const size_t MB = 1u << 20;

    // layout (185 MB total, with aliasing):
    u16* xb      = (u16*)(ws + 0);        // 16 MB (dead after QKV gemm)
    u16* wqkvT   = (u16*)(ws + 16 * MB);  // 6 MB [wq^T*QSCALE | wk^T | wv^T]
    u16* woT     = (u16*)(ws + 22 * MB);  // 2 MB
    u16* w1T     = (u16*)(ws + 24 * MB);  // 8 MB
    u16* w2T     = (u16*)(ws + 32 * MB);  // 8 MB
    float* qkvb  = (float*)(ws + 40 * MB);// 12 KB
    u16* qkv     = (u16*)(ws + 41 * MB);  // 48 MB (dead after attn)
    u16* vtb     = (u16*)(ws + 89 * MB);  // 16 MB (dead after attn)
    u16* ctxb    = (u16*)(ws + 105 * MB); // 16 MB
    float* attn_out = (float*)(ws + 121 * MB); // 32 MB (dead after add_ln1)
    float* out1     = (float*)(ws + 153 * MB); // 32 MB
    u16* out1b   = (u16*)(ws + 0);        // 16 MB, aliases dead xb
    u16* hidden  = (u16*)(ws + 41 * MB);  // 64 MB, aliases dead qkv+vtb
    float* ffn2out = (float*)(ws + 121 * MB); // aliases dead attn_out

    dim3 tb(32, 8);

    // prep: casts + weight transposes (wq pre-scaled by QSCALE = log2(e)/8)
    cast_b<<<8192, 256, 0, stream>>>(x, xb, (B_ * S_ * D_) / 4);
    transpose_cast<<<dim3(32, 32), tb, 0, stream>>>(wq, wqkvT, D_, D_, QSCALE);
    transpose_cast<<<dim3(32, 32), tb, 0, stream>>>(wk, wqkvT + 1024 * 1024, D_, D_, 1.0f);
    transpose_cast<<<dim3(32, 32), tb, 0, stream>>>(wv, wqkvT + 2048 * 1024, D_, D_, 1.0f);
    transpose_cast<<<dim3(32, 32), tb, 0, stream>>>(wo, woT, D_, D_, 1.0f);
    transpose_cast<<<dim3(128, 32), tb, 0, stream>>>(w1, w1T, D_, F_, 1.0f);
    transpose_cast<<<dim3(32, 128), tb, 0, stream>>>(w2, w2T, F_, D_, 1.0f);
    concat_bias<<<12, 256, 0, stream>>>(bq, bk, bv, qkvb);

    // fused QKV projection: [8192,1024] @ [3072,1024]^T -> qkv [8192,3072]
    gemm_bt<<<dim3(24, 64), 256, 0, stream>>>(xb, wqkvT, qkvb, nullptr, qkv,
                                              B_ * S_, QKVS, D_, 0);
    transpose_v<<<dim3(S_ / 32, DH_ / 32, B_ * H_), tb, 0, stream>>>(qkv, vtb);

    // attention (flash-style, LDS-staged K/V, XCD-clustered per (b,h))
    attn_kernel<<<dim3(B_ * H_, S_ / 128), 256, 0, stream>>>(qkv, vtb, ctxb);

    // output projection (fp32 out, residual+LN done separately)
    gemm_bt<<<dim3(8, 64), 256, 0, stream>>>(ctxb, woT, bo, attn_out, nullptr,
                                             B_ * S_, D_, D_, 0);
    add_ln<<<B_ * S_, 256, 0, stream>>>(x, attn_out, g1, be1, out1, out1b);

    // FFN
    gemm_bt<<<dim3(32, 64), 256, 0, stream>>>(out1b, w1T, b1, nullptr, hidden,
                                              B_ * S_, F_, D_, 1);
    gemm_bt<<<dim3(8, 64), 256, 0, stream>>>(hidden, w2T, b2, ffn2out, nullptr,
                                             B_ * S_, D_, F_, 0);
    add_ln<<<B_ * S_, 256, 0, stream>>>(out1, ffn2out, g2, be2, out, nullptr);
}